// Round 5
// baseline (333.876 us; speedup 1.0000x reference)
//
#include <hip/hip_runtime.h>

typedef short bfrag __attribute__((ext_vector_type(8)));   // 8 x bf16 (4 VGPRs)
typedef float facc  __attribute__((ext_vector_type(4)));   // MFMA accumulator
typedef unsigned short u16;
typedef unsigned int   u32;

#define LOG2E 1.4426950408889634f
#define MFMA(A,B,C) __builtin_amdgcn_mfma_f32_16x16x32_bf16((A),(B),(C),0,0,0)

// ---- LDS map (31488 B -> 31744 alloc -> 5 blocks/CU) ----
// Six fusion-format buffers [16][128] bf16, fsw-swizzled:
//   AS/VS/LS: softmax(a/v/l); after P3 reused as uni/bim/tri fusion.
//   AV/AL/VL: raw G (gav/gal/gvl) first, converted IN PLACE to a_v/a_l/v_l
//             during P2 (each cell read+rewritten by its owner thread).
#define AS_E 0
#define VS_E 2048
#define LS_E 4096
#define AV_E 6144
#define AL_E 8192
#define VL_E 10240
// H region: 3 x [16][64] bf16 hsw, time-multiplexed (gf-H3, gf2-H3 per pass, ll h1/h2)
#define H3_E 12288
#define SCR_B 30720    // per-row scalars: [16][12] f32 (768 B)
#define SM_BYTES 31488

__device__ __forceinline__ float ex2(float x){ return __builtin_amdgcn_exp2f(x); }
__device__ __forceinline__ float rcpf_(float x){ return __builtin_amdgcn_rcpf(x); }
__device__ __forceinline__ float ftanh(float x){ return 1.0f - 2.0f*rcpf_(ex2(x*(2.0f*LOG2E)) + 1.0f); }
__device__ __forceinline__ u16 f2b(float x){ return (u16)((__float_as_uint(x) + 0x8000u)>>16); }
__device__ __forceinline__ float b2f(u16 b){ return __uint_as_float(((u32)b)<<16); }
__device__ __forceinline__ u32 pk2(float x0, float x1){
  return __builtin_amdgcn_perm(__float_as_uint(x1)+0x8000u, __float_as_uint(x0)+0x8000u, 0x07060302u);
}
// swizzled index helpers (u16-element units); conflict-free (r4: 65K residual only)
__device__ __forceinline__ int fsw(int row, int col){ return (row*128 + col) ^ ((row&15)<<3); }
__device__ __forceinline__ int hsw(int row, int col){ return (row*64 + col) ^ ((row&7)<<3) ^ ((row&8)<<1); }

// 16-lane reductions via DPP row_ror (VALU pipe, not LDS)
template<int N>
__device__ __forceinline__ float ror16f(float v){
  return __int_as_float(__builtin_amdgcn_update_dpp(0, __float_as_int(v), 0x120|N, 0xF, 0xF, false));
}
__device__ __forceinline__ float rsum16(float v){
  v += ror16f<8>(v); v += ror16f<4>(v); v += ror16f<2>(v); v += ror16f<1>(v); return v;
}
__device__ __forceinline__ float rmax16(float v){
  v = fmaxf(v,ror16f<8>(v)); v = fmaxf(v,ror16f<4>(v));
  v = fmaxf(v,ror16f<2>(v)); v = fmaxf(v,ror16f<1>(v)); return v;
}
__device__ __forceinline__ void st4b(u16* p, float x0,float x1,float x2,float x3){
  *(uint2*)p = make_uint2(pk2(x0,x1), pk2(x2,x3));
}

// ---- prep: transpose all weight matrices to bf16 [n][k] blobs in ws ----
__global__ void prep_weights(const float* __restrict__ gf_w1, const float* __restrict__ gf_w2,
                             const float* __restrict__ gf2_w1, const float* __restrict__ gf2_w2,
                             const float* __restrict__ ll_w1, const float* __restrict__ ll_w2,
                             const float* __restrict__ ll_w3, u16* __restrict__ blob)
{
  u32 i = blockIdx.x*256u + threadIdx.x;
  if (i >= 86016u) return;
  u32 off, K, N; const float* src;
  if      (i < 16384u){ off=0u;     K=256u; N=64u;  src=gf_w1; }
  else if (i < 24576u){ off=16384u; K=64u;  N=128u; src=gf_w2; }
  else if (i < 40960u){ off=24576u; K=256u; N=64u;  src=gf2_w1; }
  else if (i < 49152u){ off=40960u; K=64u;  N=128u; src=gf2_w2; }
  else if (i < 73728u){ off=49152u; K=384u; N=64u;  src=ll_w1; }
  else if (i < 77824u){ off=73728u; K=64u;  N=64u;  src=ll_w2; }
  else               { off=77824u; K=64u;  N=128u; src=ll_w3; }
  u32 li = i - off, n = li / K, k = li - n*K;
  blob[i] = f2b(src[k*N + n]);   // wt[n][k] = w[k][n]
}

__global__ __launch_bounds__(256,5) void fused_graph(
    const float* __restrict__ Lg, const float* __restrict__ Ag, const float* __restrict__ Vg,
    const float* __restrict__ att_w, const float* __restrict__ att_b,
    const float* __restrict__ gf_b1, const float* __restrict__ gf_b2,
    const float* __restrict__ gf2_b1, const float* __restrict__ gf2_b2,
    const float* __restrict__ ll_b1, const float* __restrict__ ll_b2, const float* __restrict__ ll_b3,
    const u16* __restrict__ wb, float* __restrict__ out)
{
  __shared__ alignas(16) char sm[SM_BYTES];
  u16* smu = (u16*)sm;
  float* scr = (float*)(sm + SCR_B);

  const int tid = threadIdx.x;
  const int lane = tid & 63;
  const int w = tid >> 6;        // wave 0..3
  const int m = lane & 15;       // MFMA row(A)/col(B)/col(C)
  const int q = lane >> 4;       // quad
  const int er = tid >> 4;       // elementwise row 0..15
  const int ep = tid & 15;       // elementwise lane-in-row
  const int row0 = blockIdx.x << 4;

  // ================= P0: attention scalars, unimodal(->regs), softmaxes, dots =================
  const int gb = (row0 + er)*128 + ep*4;
  facc A0 = *(const facc*)(Ag+gb), A1 = *(const facc*)(Ag+gb+64);
  facc V0 = *(const facc*)(Vg+gb), V1 = *(const facc*)(Vg+gb+64);
  facc L0 = *(const facc*)(Lg+gb), L1 = *(const facc*)(Lg+gb+64);
  facc W0 = *(const facc*)(att_w+ep*4), W1 = *(const facc*)(att_w+ep*4+64);
  float ab = att_b[0];
  float pa=0.f,pv=0.f,pl=0.f;
  #pragma unroll
  for (int i=0;i<4;i++){ pa += A0[i]*W0[i]+A1[i]*W1[i]; pv += V0[i]*W0[i]+V1[i]*W1[i]; pl += L0[i]*W0[i]+L1[i]*W1[i]; }
  float sa = ftanh(rsum16(pa)+ab), sv = ftanh(rsum16(pv)+ab), sl = ftanh(rsum16(pl)+ab);
  u32 uni_pk[4];
  {
    const float th = 1.0f/3.0f;
    uni_pk[0] = pk2((sa*A0[0]+sv*V0[0]+sl*L0[0])*th, (sa*A0[1]+sv*V0[1]+sl*L0[1])*th);
    uni_pk[1] = pk2((sa*A0[2]+sv*V0[2]+sl*L0[2])*th, (sa*A0[3]+sv*V0[3]+sl*L0[3])*th);
    uni_pk[2] = pk2((sa*A1[0]+sv*V1[0]+sl*L1[0])*th, (sa*A1[1]+sv*V1[1]+sl*L1[1])*th);
    uni_pk[3] = pk2((sa*A1[2]+sv*V1[2]+sl*L1[2])*th, (sa*A1[3]+sv*V1[3]+sl*L1[3])*th);
  }
  #define SMAX(X0,X1,OFFE) { \
    float mx=-3.0e38f; \
    _Pragma("unroll") for (int i=0;i<4;i++){ mx=fmaxf(mx,fmaxf(X0[i],X1[i])); } \
    mx = rmax16(mx); float s_=0.f; \
    _Pragma("unroll") for (int i=0;i<4;i++){ X0[i]=ex2((X0[i]-mx)*LOG2E); X1[i]=ex2((X1[i]-mx)*LOG2E); s_+=X0[i]+X1[i]; } \
    s_ = rsum16(s_); float rs_ = rcpf_(s_); \
    _Pragma("unroll") for (int i=0;i<4;i++){ X0[i]*=rs_; X1[i]*=rs_; } \
    st4b(smu + (OFFE) + fsw(er, ep*4),    X0[0],X0[1],X0[2],X0[3]); \
    st4b(smu + (OFFE) + fsw(er, ep*4+64), X1[0],X1[1],X1[2],X1[3]); }
  SMAX(A0,A1,AS_E)
  SMAX(V0,V1,VS_E)
  SMAX(L0,L1,LS_E)
  float dav=0.f,dal=0.f,dvl=0.f;
  #pragma unroll
  for (int i=0;i<4;i++){ dav += A0[i]*V0[i]+A1[i]*V1[i]; dal += A0[i]*L0[i]+A1[i]*L1[i]; dvl += V0[i]*L0[i]+V1[i]*L1[i]; }
  dav = rsum16(dav); dal = rsum16(dal); dvl = rsum16(dvl);
  float sav = (sa+sv)*rcpf_(dav+0.5f);
  float sal = (sa+sl)*rcpf_(dal+0.5f);
  float svl = (sl+sv)*rcpf_(dvl+0.5f);
  if (ep==0){
    float mx = fmaxf(sav,fmaxf(sal,svl));
    float e0 = ex2((sav-mx)*LOG2E), e1 = ex2((sal-mx)*LOG2E), e2 = ex2((svl-mx)*LOG2E);
    float rs = rcpf_(e0+e1+e2);
    scr[er*12+0]=e0*rs; scr[er*12+1]=e1*rs; scr[er*12+2]=e2*rs;
  }
  // A0..L1 die here (P2 dots read the bf16 LDS copies) -> -24 arch VGPRs
  __syncthreads();   // (1) softmaxes + scr[0..2] ready

  // ================= P1: gf on 3 pairs =================
  const u16* g1t = wb;            // [64][256]
  const u16* g2t = wb + 16384;    // [128][64]
  bfrag B1[8];
  #pragma unroll
  for (int s=0;s<8;s++) B1[s] = *(const bfrag*)(g1t + (w*16+m)*256 + s*32 + q*8);
  facc acc0={0,0,0,0}, acc1={0,0,0,0}, acc2={0,0,0,0};
  #pragma unroll
  for (int s=0;s<8;s++){
    int k = s*32 + q*8, ko = k & 127; bool hi = (k >= 128);
    const u16* p0 = smu + (hi? VS_E:AS_E) + fsw(m, ko);  // (a',v')
    const u16* p1 = smu + (hi? LS_E:AS_E) + fsw(m, ko);  // (a',l')
    const u16* p2 = smu + (hi? LS_E:VS_E) + fsw(m, ko);  // (v',l')
    acc0 = MFMA(*(const bfrag*)p0, B1[s], acc0);
    acc1 = MFMA(*(const bfrag*)p1, B1[s], acc1);
    acc2 = MFMA(*(const bfrag*)p2, B1[s], acc2);
  }
  { // leaky_relu -> H3 (hsw [16][64] x3)
    float b1v = gf_b1[w*16+m];
    #pragma unroll
    for (int r=0;r<4;r++){
      int rr = q*4+r;
      float h0 = acc0[r]+b1v; h0 = fmaxf(h0, 0.2f*h0);
      float h1 = acc1[r]+b1v; h1 = fmaxf(h1, 0.2f*h1);
      float h2 = acc2[r]+b1v; h2 = fmaxf(h2, 0.2f*h2);
      smu[H3_E + 0*1024 + hsw(rr, w*16+m)] = f2b(h0);
      smu[H3_E + 1*1024 + hsw(rr, w*16+m)] = f2b(h1);
      smu[H3_E + 2*1024 + hsw(rr, w*16+m)] = f2b(h2);
    }
  }
  __syncthreads();   // (2) H3 ready
  facc c2[3][2] = {{{0,0,0,0},{0,0,0,0}},{{0,0,0,0},{0,0,0,0}},{{0,0,0,0},{0,0,0,0}}};
  #pragma unroll
  for (int s=0;s<2;s++){
    int k = s*32 + q*8;
    bfrag Af0 = *(const bfrag*)(smu + H3_E + 0*1024 + hsw(m, k));
    bfrag Af1 = *(const bfrag*)(smu + H3_E + 1*1024 + hsw(m, k));
    bfrag Af2 = *(const bfrag*)(smu + H3_E + 2*1024 + hsw(m, k));
    #pragma unroll
    for (int t=0;t<2;t++){
      bfrag B2f = *(const bfrag*)(g2t + ((w+4*t)*16+m)*64 + s*32 + q*8);  // late load, L2-hot
      c2[0][t] = MFMA(Af0, B2f, c2[0][t]);
      c2[1][t] = MFMA(Af1, B2f, c2[1][t]);
      c2[2][t] = MFMA(Af2, B2f, c2[2][t]);
    }
  }
  // NO barrier: G goes to AV/AL/VL (untouched region), H3 only read in-wave above.
  { // raw G -> AV/AL/VL slots (converted in place during P2)
    float b2v0 = gf_b2[w*16+m], b2v1 = gf_b2[(w+4)*16+m];
    #pragma unroll
    for (int p3=0;p3<3;p3++){
      #pragma unroll
      for (int t=0;t<2;t++){
        float bb = t? b2v1 : b2v0;
        int cc = (w+4*t)*16+m;
        #pragma unroll
        for (int r=0;r<4;r++){
          smu[AV_E + p3*2048 + fsw(q*4+r, cc)] = f2b(ftanh(c2[p3][t][r] + bb));
        }
      }
    }
  }
  __syncthreads();   // (3) G ready

  // ======== P2: softmax stats of G + IN-PLACE a_v/a_l/v_l conversion + dots + n2 ========
  float E0[8], E1[8], E2[8], bim8[8];
  #pragma unroll
  for (int j=0;j<8;j++) bim8[j]=0.f;
  // Each G cell is loaded, stat'ed, and rewritten tanh(n*g) by its OWNER thread only.
  #define GSTATC(EA, G3) { \
    u16* gpa_ = smu + AV_E + (G3)*2048 + fsw(er, ep*4); \
    u16* gpb_ = smu + AV_E + (G3)*2048 + fsw(er, ep*4+64); \
    ushort4 ga_ = *(const ushort4*)gpa_; ushort4 gb_ = *(const ushort4*)gpb_; \
    float x_[8]; \
    x_[0]=b2f(ga_.x); x_[1]=b2f(ga_.y); x_[2]=b2f(ga_.z); x_[3]=b2f(ga_.w); \
    x_[4]=b2f(gb_.x); x_[5]=b2f(gb_.y); x_[6]=b2f(gb_.z); x_[7]=b2f(gb_.w); \
    float nn_ = scr[er*12+(G3)]; \
    float t_[8]; \
    _Pragma("unroll") for (int j=0;j<8;j++){ t_[j]=ftanh(nn_*x_[j]); bim8[j]+=t_[j]; } \
    st4b(gpa_, t_[0],t_[1],t_[2],t_[3]); \
    st4b(gpb_, t_[4],t_[5],t_[6],t_[7]); \
    float mx_=-3.0e38f; \
    _Pragma("unroll") for (int j=0;j<8;j++) mx_=fmaxf(mx_,x_[j]); \
    mx_ = rmax16(mx_); float s_=0.f; \
    _Pragma("unroll") for (int j=0;j<8;j++){ x_[j]=ex2((x_[j]-mx_)*LOG2E); s_+=x_[j]; } \
    s_ = rsum16(s_); float rs_=rcpf_(s_); \
    _Pragma("unroll") for (int j=0;j<8;j++) EA[j]=x_[j]*rs_; }
  GSTATC(E0,0)
  GSTATC(E1,1)
  GSTATC(E2,2)
  #define LD8(DST, OFFE) { \
    const u16* pa_ = smu + (OFFE) + fsw(er, ep*4); \
    const u16* pb_ = smu + (OFFE) + fsw(er, ep*4+64); \
    ushort4 a_ = *(const ushort4*)pa_; ushort4 b_ = *(const ushort4*)pb_; \
    DST[0]=b2f(a_.x); DST[1]=b2f(a_.y); DST[2]=b2f(a_.z); DST[3]=b2f(a_.w); \
    DST[4]=b2f(b_.x); DST[5]=b2f(b_.y); DST[6]=b2f(b_.z); DST[7]=b2f(b_.w); }
  float lv8[8], vv8[8], av8[8];
  LD8(lv8, LS_E)
  LD8(vv8, VS_E)
  LD8(av8, AS_E)
  float d01=0.f,d02=0.f,d12=0.f,d0l=0.f,d1v=0.f,d2a=0.f;
  #pragma unroll
  for (int j=0;j<8;j++){
    d01 += E0[j]*E1[j]; d02 += E0[j]*E2[j]; d12 += E1[j]*E2[j];
    d0l += E0[j]*lv8[j]; d1v += E1[j]*vv8[j]; d2a += E2[j]*av8[j];
  }
  d01=rsum16(d01); d02=rsum16(d02); d12=rsum16(d12);
  d0l=rsum16(d0l); d1v=rsum16(d1v); d2a=rsum16(d2a);
  if (ep==0){
    float x0 = (sav+svl)*rcpf_(d02+0.5f);  // savvl
    float x1 = (sav+sal)*rcpf_(d01+0.5f);  // saavl
    float x2 = (sal+svl)*rcpf_(d12+0.5f);  // savll
    float x3 = (sav+sl )*rcpf_(d0l+0.5f);  // savl
    float x4 = (sal+sv )*rcpf_(d1v+0.5f);  // salv
    float x5 = (sa +svl)*rcpf_(d2a+0.5f);  // svla
    float mx = fmaxf(fmaxf(fmaxf(x0,x1),fmaxf(x2,x3)),fmaxf(x4,x5));
    float e0=ex2((x0-mx)*LOG2E), e1=ex2((x1-mx)*LOG2E), e2=ex2((x2-mx)*LOG2E);
    float e3=ex2((x3-mx)*LOG2E), e4=ex2((x4-mx)*LOG2E), e5=ex2((x5-mx)*LOG2E);
    float rs = rcpf_(e0+e1+e2+e3+e4+e5);
    scr[er*12+3]=e0*rs; scr[er*12+4]=e1*rs; scr[er*12+5]=e2*rs;
    scr[er*12+6]=e3*rs; scr[er*12+7]=e4*rs; scr[er*12+8]=e5*rs;
  }
  __syncthreads();   // (4) conversions + n2 ready

  // ================= P3: gf2 on 6 pairs in 2 passes of 3 =================
  const u16* h1t = wb + 24576;
  const u16* h2t = wb + 40960;
  bfrag C1[8];
  #pragma unroll
  for (int s=0;s<8;s++) C1[s] = *(const bfrag*)(h1t + (w*16+m)*256 + s*32 + q*8);
  const int PB0[6] = {AV_E, AV_E, VL_E, AV_E, AL_E, VL_E};
  const int PB1[6] = {VL_E, AL_E, AL_E, LS_E, VS_E, AS_E};
  float tri[2][4] = {{0,0,0,0},{0,0,0,0}};
  float b1v2 = gf2_b1[w*16+m];
  float b2v0_ = gf2_b2[w*16+m], b2v1_ = gf2_b2[(w+4)*16+m];
  #pragma unroll
  for (int ps=0; ps<2; ps++){
    facc cc1[3];
    #pragma unroll
    for (int pl=0;pl<3;pl++){ facc z = {0,0,0,0}; cc1[pl] = z; }
    #pragma unroll
    for (int s=0;s<8;s++){
      int k = s*32+q*8, ko = k&127; bool hi = (k>=128);
      #pragma unroll
      for (int pl=0;pl<3;pl++){
        int pr = ps*3+pl;
        const u16* sp = smu + (hi? PB1[pr]:PB0[pr]) + fsw(m, ko);
        cc1[pl] = MFMA(*(const bfrag*)sp, C1[s], cc1[pl]);
      }
    }
    #pragma unroll
    for (int pl=0;pl<3;pl++){
      #pragma unroll
      for (int r=0;r<4;r++){
        float h = cc1[pl][r]+b1v2; h = fmaxf(h,0.2f*h);
        smu[H3_E + pl*1024 + hsw(q*4+r, w*16+m)] = f2b(h);
      }
    }
    __syncthreads();   // (5a/5c) H3 of this pass ready
    facc cc2[3][2];
    #pragma unroll
    for (int pl=0;pl<3;pl++){ facc z = {0,0,0,0}; cc2[pl][0]=z; cc2[pl][1]=z; }
    #pragma unroll
    for (int s=0;s<2;s++){
      int k=s*32+q*8;
      bfrag Af0 = *(const bfrag*)(smu + H3_E + 0*1024 + hsw(m, k));
      bfrag Af1 = *(const bfrag*)(smu + H3_E + 1*1024 + hsw(m, k));
      bfrag Af2 = *(const bfrag*)(smu + H3_E + 2*1024 + hsw(m, k));
      #pragma unroll
      for (int t=0;t<2;t++){
        bfrag C2f = *(const bfrag*)(h2t + ((w+4*t)*16+m)*64 + s*32 + q*8);  // late load, L2-hot
        cc2[0][t] = MFMA(Af0, C2f, cc2[0][t]);
        cc2[1][t] = MFMA(Af1, C2f, cc2[1][t]);
        cc2[2][t] = MFMA(Af2, C2f, cc2[2][t]);
      }
    }
    #pragma unroll
    for (int pl=0;pl<3;pl++){
      #pragma unroll
      for (int t=0;t<2;t++){
        float bb = t? b2v1_ : b2v0_;
        #pragma unroll
        for (int r=0;r<4;r++){
          float g = ftanh(cc2[pl][t][r] + bb);
          float nn = scr[(q*4+r)*12+3+ps*3+pl];
          tri[t][r] += ftanh(nn*g);
        }
      }
    }
    if (ps==0) __syncthreads();   // (5b) pass-A H3 consumed
  }
  { // fusion = [uni|bim|tri] -> AS|VS|LS (all cc1 reads finished before sync 5c)
    #pragma unroll
    for (int t=0;t<2;t++){
      #pragma unroll
      for (int r=0;r<4;r++){
        smu[LS_E + fsw(q*4+r, (w+4*t)*16+m)] = f2b(tri[t][r]);
      }
    }
    st4b(smu + VS_E + fsw(er, ep*4),    bim8[0],bim8[1],bim8[2],bim8[3]);
    st4b(smu + VS_E + fsw(er, ep*4+64), bim8[4],bim8[5],bim8[6],bim8[7]);
    *(uint2*)(smu + AS_E + fsw(er, ep*4))    = make_uint2(uni_pk[0], uni_pk[1]);
    *(uint2*)(smu + AS_E + fsw(er, ep*4+64)) = make_uint2(uni_pk[2], uni_pk[3]);
  }
  __syncthreads();   // (6) fusion complete (AS|VS|LS)

  // ================= P4: final head 384->64->64->128 =================
  const u16* lw1 = wb + 49152;
  const u16* lw2 = wb + 73728;
  const u16* lw3 = wb + 77824;
  {
    facc c = {0,0,0,0};
    #pragma unroll
    for (int s=0;s<12;s++){
      const int base = (s<4)? AS_E : (s<8)? VS_E : LS_E;
      bfrag Bf = *(const bfrag*)(lw1 + (w*16+m)*384 + s*32 + q*8);
      bfrag Af = *(const bfrag*)(smu + base + fsw(m, (s&3)*32 + q*8));
      c = MFMA(Af, Bf, c);
    }
    float b = ll_b1[w*16+m];
    #pragma unroll
    for (int r=0;r<4;r++) smu[H3_E + hsw(q*4+r, w*16+m)] = f2b(ftanh(c[r]+b));
  }
  __syncthreads();   // (7)
  {
    facc c = {0,0,0,0};
    #pragma unroll
    for (int s=0;s<2;s++){
      bfrag Bf = *(const bfrag*)(lw2 + (w*16+m)*64 + s*32 + q*8);
      bfrag Af = *(const bfrag*)(smu + H3_E + hsw(m, s*32 + q*8));
      c = MFMA(Af, Bf, c);
    }
    float b = ll_b2[w*16+m];
    #pragma unroll
    for (int r=0;r<4;r++) smu[H3_E + 1024 + hsw(q*4+r, w*16+m)] = f2b(ftanh(c[r]+b));
  }
  __syncthreads();   // (8)
  {
    facc c0={0,0,0,0}, c1={0,0,0,0};
    #pragma unroll
    for (int s=0;s<2;s++){
      bfrag Af  = *(const bfrag*)(smu + H3_E + 1024 + hsw(m, s*32 + q*8));
      bfrag Bf0 = *(const bfrag*)(lw3 + (w*16+m)*64 + s*32 + q*8);
      bfrag Bf1 = *(const bfrag*)(lw3 + ((w+4)*16+m)*64 + s*32 + q*8);
      c0 = MFMA(Af, Bf0, c0);
      c1 = MFMA(Af, Bf1, c1);
    }
    float b0 = ll_b3[w*16+m], b1 = ll_b3[(w+4)*16+m];
    #pragma unroll
    for (int r=0;r<4;r++){
      out[(row0+q*4+r)*128 + w*16+m]     = ftanh(c0[r]+b0);
      out[(row0+q*4+r)*128 + (w+4)*16+m] = ftanh(c1[r]+b1);
    }
  }
}

extern "C" void kernel_launch(void* const* d_in, const int* in_sizes, int n_in,
                              void* d_out, int out_size, void* d_ws, size_t ws_size,
                              hipStream_t stream)
{
  const float* l      = (const float*)d_in[0];
  const float* a      = (const float*)d_in[1];
  const float* v      = (const float*)d_in[2];
  const float* att_w  = (const float*)d_in[3];
  const float* att_b  = (const float*)d_in[4];
  const float* gf_w1  = (const float*)d_in[5];
  const float* gf_b1  = (const float*)d_in[6];
  const float* gf_w2  = (const float*)d_in[7];
  const float* gf_b2  = (const float*)d_in[8];
  const float* gf2_w1 = (const float*)d_in[9];
  const float* gf2_b1 = (const float*)d_in[10];
  const float* gf2_w2 = (const float*)d_in[11];
  const float* gf2_b2 = (const float*)d_in[12];
  const float* ll_w1  = (const float*)d_in[13];
  const float* ll_b1  = (const float*)d_in[14];
  const float* ll_w2  = (const float*)d_in[15];
  const float* ll_b2  = (const float*)d_in[16];
  const float* ll_w3  = (const float*)d_in[17];
  const float* ll_b3  = (const float*)d_in[18];
  u16* blob = (u16*)d_ws;

  prep_weights<<<336, 256, 0, stream>>>(gf_w1, gf_w2, gf2_w1, gf2_w2, ll_w1, ll_w2, ll_w3, blob);
  fused_graph<<<4096, 256, 0, stream>>>(l, a, v, att_w, att_b,
                                        gf_b1, gf_b2, gf2_b1, gf2_b2,
                                        ll_b1, ll_b2, ll_b3, blob, (float*)d_out);
}

// Round 6
// 247.086 us; speedup vs baseline: 1.3513x; 1.3513x over previous
//
#include <hip/hip_runtime.h>

typedef short bfrag __attribute__((ext_vector_type(8)));   // 8 x bf16 (4 VGPRs)
typedef float facc  __attribute__((ext_vector_type(4)));   // MFMA accumulator
typedef unsigned short u16;
typedef unsigned int   u32;

#define LOG2E 1.4426950408889634f
#define MFMA(A,B,C) __builtin_amdgcn_mfma_f32_16x16x32_bf16((A),(B),(C),0,0,0)

// ---- LDS element offsets (u16 units) — round-0 padded map (proven 152 us) ----
// AS/VS/LS: softmax(a/v/l) [16][136]; after P3-cc1 reused as uni/bim/tri fusion.
// AV/AL/VL: raw G (gav/gal/gvl) first, converted IN PLACE to a_v/a_l/v_l in P2.
#define AS_E 0
#define VS_E 2176
#define LS_E 4352
#define AV_E 6528
#define AL_E 8704
#define VL_E 10880
// HH region (6912 elems): H3 (3x[16][72]) -> H6 (6x[16][72]) -> ll scratch (2x[16][72])
#define HH_E 13056
#define SCR_B 39936       // per-row scalars: [16][12] f32 (768 B)
#define SM_BYTES 40704    // -> 40960 alloc; 4 blocks/CU (register-capped anyway)

__device__ __forceinline__ float ex2(float x){ return __builtin_amdgcn_exp2f(x); }
__device__ __forceinline__ float rcpf_(float x){ return __builtin_amdgcn_rcpf(x); }
__device__ __forceinline__ float ftanh(float x){ return 1.0f - 2.0f*rcpf_(ex2(x*(2.0f*LOG2E)) + 1.0f); }
__device__ __forceinline__ u16 f2b(float x){ return (u16)((__float_as_uint(x) + 0x8000u)>>16); }
__device__ __forceinline__ float b2f(u16 b){ return __uint_as_float(((u32)b)<<16); }
__device__ __forceinline__ u32 pk2(float x0, float x1){
  return __builtin_amdgcn_perm(__float_as_uint(x1)+0x8000u, __float_as_uint(x0)+0x8000u, 0x07060302u);
}
// 16-lane reductions via DPP row_ror (VALU pipe, not LDS)
template<int N>
__device__ __forceinline__ float ror16f(float v){
  return __int_as_float(__builtin_amdgcn_update_dpp(0, __float_as_int(v), 0x120|N, 0xF, 0xF, false));
}
__device__ __forceinline__ float rsum16(float v){
  v += ror16f<8>(v); v += ror16f<4>(v); v += ror16f<2>(v); v += ror16f<1>(v); return v;
}
__device__ __forceinline__ float rmax16(float v){
  v = fmaxf(v,ror16f<8>(v)); v = fmaxf(v,ror16f<4>(v));
  v = fmaxf(v,ror16f<2>(v)); v = fmaxf(v,ror16f<1>(v)); return v;
}
__device__ __forceinline__ void st4b(u16* p, float x0,float x1,float x2,float x3){
  *(uint2*)p = make_uint2(pk2(x0,x1), pk2(x2,x3));
}

// ---- prep: transpose weights to bf16 [n][k] blobs; COALESCED reads (r6) ----
__global__ void prep_weights(const float* __restrict__ gf_w1, const float* __restrict__ gf_w2,
                             const float* __restrict__ gf2_w1, const float* __restrict__ gf2_w2,
                             const float* __restrict__ ll_w1, const float* __restrict__ ll_w2,
                             const float* __restrict__ ll_w3, u16* __restrict__ blob)
{
  u32 i = blockIdx.x*256u + threadIdx.x;
  if (i >= 86016u) return;
  u32 off, K, ln; const float* src;   // ln = log2(N), N in {64,128}
  if      (i < 16384u){ off=0u;     K=256u; ln=6u; src=gf_w1; }
  else if (i < 24576u){ off=16384u; K=64u;  ln=7u; src=gf_w2; }
  else if (i < 40960u){ off=24576u; K=256u; ln=6u; src=gf2_w1; }
  else if (i < 49152u){ off=40960u; K=64u;  ln=7u; src=gf2_w2; }
  else if (i < 73728u){ off=49152u; K=384u; ln=6u; src=ll_w1; }
  else if (i < 77824u){ off=73728u; K=64u;  ln=6u; src=ll_w2; }
  else               { off=77824u; K=64u;  ln=7u; src=ll_w3; }
  u32 li = i - off;                  // input-linear: li = k*N + n
  u32 k = li >> ln, n = li & ((1u<<ln)-1u);
  blob[off + n*K + k] = f2b(src[li]);   // coalesced load, scattered (fire-and-forget) store
}

__global__ __launch_bounds__(256,4) void fused_graph(
    const float* __restrict__ Lg, const float* __restrict__ Ag, const float* __restrict__ Vg,
    const float* __restrict__ att_w, const float* __restrict__ att_b,
    const float* __restrict__ gf_b1, const float* __restrict__ gf_b2,
    const float* __restrict__ gf2_b1, const float* __restrict__ gf2_b2,
    const float* __restrict__ ll_b1, const float* __restrict__ ll_b2, const float* __restrict__ ll_b3,
    const u16* __restrict__ wb, float* __restrict__ out)
{
  __shared__ alignas(16) char sm[SM_BYTES];
  u16* smu = (u16*)sm;
  float* scr = (float*)(sm + SCR_B);

  const int tid = threadIdx.x;
  const int lane = tid & 63;
  const int w = tid >> 6;        // wave 0..3
  const int m = lane & 15;       // MFMA row(A)/col(B)/col(C)
  const int q = lane >> 4;       // quad
  const int er = tid >> 4;       // elementwise row 0..15
  const int ep = tid & 15;       // elementwise lane-in-row
  const int row0 = blockIdx.x << 4;

  // ================= P0: attention scalars, unimodal(->regs), softmaxes, dots =================
  const int gb = (row0 + er)*128 + ep*4;
  facc A0 = *(const facc*)(Ag+gb), A1 = *(const facc*)(Ag+gb+64);
  facc V0 = *(const facc*)(Vg+gb), V1 = *(const facc*)(Vg+gb+64);
  facc L0 = *(const facc*)(Lg+gb), L1 = *(const facc*)(Lg+gb+64);
  facc W0 = *(const facc*)(att_w+ep*4), W1 = *(const facc*)(att_w+ep*4+64);
  float ab = att_b[0];
  float pa=0.f,pv=0.f,pl=0.f;
  #pragma unroll
  for (int i=0;i<4;i++){ pa += A0[i]*W0[i]+A1[i]*W1[i]; pv += V0[i]*W0[i]+V1[i]*W1[i]; pl += L0[i]*W0[i]+L1[i]*W1[i]; }
  float sa = ftanh(rsum16(pa)+ab), sv = ftanh(rsum16(pv)+ab), sl = ftanh(rsum16(pl)+ab);
  // unimodal: pack to 4 u32 (bf16x2), stored to LDS at P3-end when AS frees up
  u32 uni_pk[4];
  {
    const float th = 1.0f/3.0f;
    uni_pk[0] = pk2((sa*A0[0]+sv*V0[0]+sl*L0[0])*th, (sa*A0[1]+sv*V0[1]+sl*L0[1])*th);
    uni_pk[1] = pk2((sa*A0[2]+sv*V0[2]+sl*L0[2])*th, (sa*A0[3]+sv*V0[3]+sl*L0[3])*th);
    uni_pk[2] = pk2((sa*A1[0]+sv*V1[0]+sl*L1[0])*th, (sa*A1[1]+sv*V1[1]+sl*L1[1])*th);
    uni_pk[3] = pk2((sa*A1[2]+sv*V1[2]+sl*L1[2])*th, (sa*A1[3]+sv*V1[3]+sl*L1[3])*th);
  }
  #define SMAX(X0,X1,OFFE) { \
    float mx=-3.0e38f; \
    _Pragma("unroll") for (int i=0;i<4;i++){ mx=fmaxf(mx,fmaxf(X0[i],X1[i])); } \
    mx = rmax16(mx); float s_=0.f; \
    _Pragma("unroll") for (int i=0;i<4;i++){ X0[i]=ex2((X0[i]-mx)*LOG2E); X1[i]=ex2((X1[i]-mx)*LOG2E); s_+=X0[i]+X1[i]; } \
    s_ = rsum16(s_); float rs_ = rcpf_(s_); \
    _Pragma("unroll") for (int i=0;i<4;i++){ X0[i]*=rs_; X1[i]*=rs_; } \
    u16* dp_ = smu + (OFFE) + er*136 + ep*4; \
    st4b(dp_, X0[0],X0[1],X0[2],X0[3]); st4b(dp_+64, X1[0],X1[1],X1[2],X1[3]); }
  SMAX(A0,A1,AS_E)
  SMAX(V0,V1,VS_E)
  SMAX(L0,L1,LS_E)
  float dav=0.f,dal=0.f,dvl=0.f;
  #pragma unroll
  for (int i=0;i<4;i++){ dav += A0[i]*V0[i]+A1[i]*V1[i]; dal += A0[i]*L0[i]+A1[i]*L1[i]; dvl += V0[i]*L0[i]+V1[i]*L1[i]; }
  dav = rsum16(dav); dal = rsum16(dal); dvl = rsum16(dvl);
  float sav = (sa+sv)*rcpf_(dav+0.5f);
  float sal = (sa+sl)*rcpf_(dal+0.5f);
  float svl = (sl+sv)*rcpf_(dvl+0.5f);
  if (ep==0){
    float mx = fmaxf(sav,fmaxf(sal,svl));
    float e0 = ex2((sav-mx)*LOG2E), e1 = ex2((sal-mx)*LOG2E), e2 = ex2((svl-mx)*LOG2E);
    float rs = rcpf_(e0+e1+e2);
    scr[er*12+0]=e0*rs; scr[er*12+1]=e1*rs; scr[er*12+2]=e2*rs;
  }
  __syncthreads();   // (1) softmaxes+scr ready

  // ================= P1: gf on 3 pairs =================
  const u16* g1t = wb;            // [64][256]
  const u16* g2t = wb + 16384;    // [128][64]
  bfrag B1[8];
  #pragma unroll
  for (int s=0;s<8;s++) B1[s] = *(const bfrag*)(g1t + (w*16+m)*256 + s*32 + q*8);
  facc acc0={0,0,0,0}, acc1={0,0,0,0}, acc2={0,0,0,0};
  #pragma unroll
  for (int s=0;s<8;s++){
    int k = s*32 + q*8, ko = k & 127; bool hi = (k >= 128);
    const u16* p0 = smu + (hi? VS_E:AS_E) + m*136 + ko;  // (a',v')
    const u16* p1 = smu + (hi? LS_E:AS_E) + m*136 + ko;  // (a',l')
    const u16* p2 = smu + (hi? LS_E:VS_E) + m*136 + ko;  // (v',l')
    acc0 = MFMA(*(const bfrag*)p0, B1[s], acc0);
    acc1 = MFMA(*(const bfrag*)p1, B1[s], acc1);
    acc2 = MFMA(*(const bfrag*)p2, B1[s], acc2);
  }
  { // leaky_relu -> H3 @ HH_E (stride 72)
    float b1v = gf_b1[w*16+m];
    #pragma unroll
    for (int r=0;r<4;r++){
      int rr = q*4+r;
      float h0 = acc0[r]+b1v; h0 = fmaxf(h0, 0.2f*h0);
      float h1 = acc1[r]+b1v; h1 = fmaxf(h1, 0.2f*h1);
      float h2 = acc2[r]+b1v; h2 = fmaxf(h2, 0.2f*h2);
      smu[HH_E + 0*1152 + rr*72 + w*16+m] = f2b(h0);
      smu[HH_E + 1*1152 + rr*72 + w*16+m] = f2b(h1);
      smu[HH_E + 2*1152 + rr*72 + w*16+m] = f2b(h2);
    }
  }
  __syncthreads();   // (2) H3 ready
  facc c2[3][2] = {{{0,0,0,0},{0,0,0,0}},{{0,0,0,0},{0,0,0,0}},{{0,0,0,0},{0,0,0,0}}};
  #pragma unroll
  for (int s=0;s<2;s++){
    int k = s*32 + q*8;
    bfrag Af0 = *(const bfrag*)(smu + HH_E + 0*1152 + m*72 + k);
    bfrag Af1 = *(const bfrag*)(smu + HH_E + 1*1152 + m*72 + k);
    bfrag Af2 = *(const bfrag*)(smu + HH_E + 2*1152 + m*72 + k);
    #pragma unroll
    for (int t=0;t<2;t++){
      bfrag B2f = *(const bfrag*)(g2t + ((w+4*t)*16+m)*64 + s*32 + q*8);  // late load, L2-hot
      c2[0][t] = MFMA(Af0, B2f, c2[0][t]);
      c2[1][t] = MFMA(Af1, B2f, c2[1][t]);
      c2[2][t] = MFMA(Af2, B2f, c2[2][t]);
    }
  }
  // NO barrier: raw G goes to AV/AL/VL (first write to that region); H3 reads were in-wave.
  {
    float b2v0 = gf_b2[w*16+m], b2v1 = gf_b2[(w+4)*16+m];
    #pragma unroll
    for (int p3=0;p3<3;p3++){
      #pragma unroll
      for (int t=0;t<2;t++){
        float bb = t? b2v1 : b2v0;
        int cc = (w+4*t)*16+m;
        #pragma unroll
        for (int r=0;r<4;r++){
          smu[AV_E + p3*2176 + (q*4+r)*136 + cc] = f2b(ftanh(c2[p3][t][r] + bb));
        }
      }
    }
  }
  __syncthreads();   // (3) raw G ready

  // ======== P2: max-free softmax stats of G + IN-PLACE a_v/a_l/v_l conversion + dots + n2 ========
  // g = tanh(.) in (-1,1) => no max subtraction needed: e = exp2(g*log2e)  [validated r5]
  float E0[8], E1[8], E2[8], bim8[8];
  #pragma unroll
  for (int j=0;j<8;j++) bim8[j]=0.f;
  #define GSTATC(EA, G3) { \
    u16* gpa_ = smu + AV_E + (G3)*2176 + er*136 + ep*4; \
    u16* gpb_ = gpa_ + 64; \
    ushort4 ga_ = *(const ushort4*)gpa_; ushort4 gb_ = *(const ushort4*)gpb_; \
    float x_[8]; \
    x_[0]=b2f(ga_.x); x_[1]=b2f(ga_.y); x_[2]=b2f(ga_.z); x_[3]=b2f(ga_.w); \
    x_[4]=b2f(gb_.x); x_[5]=b2f(gb_.y); x_[6]=b2f(gb_.z); x_[7]=b2f(gb_.w); \
    float nn_ = scr[er*12+(G3)]; \
    float t_[8]; \
    _Pragma("unroll") for (int j=0;j<8;j++){ t_[j]=ftanh(nn_*x_[j]); bim8[j]+=t_[j]; } \
    st4b(gpa_, t_[0],t_[1],t_[2],t_[3]); \
    st4b(gpb_, t_[4],t_[5],t_[6],t_[7]); \
    float s_=0.f; \
    _Pragma("unroll") for (int j=0;j<8;j++){ x_[j]=ex2(x_[j]*LOG2E); s_+=x_[j]; } \
    s_ = rsum16(s_); float rs_=rcpf_(s_); \
    _Pragma("unroll") for (int j=0;j<8;j++) EA[j]=x_[j]*rs_; }
  GSTATC(E0,0)
  GSTATC(E1,1)
  GSTATC(E2,2)
  float d01=0.f,d02=0.f,d12=0.f,d0l=0.f,d1v=0.f,d2a=0.f;
  #pragma unroll
  for (int i=0;i<4;i++){
    d01 += E0[i]*E1[i] + E0[4+i]*E1[4+i];
    d02 += E0[i]*E2[i] + E0[4+i]*E2[4+i];
    d12 += E1[i]*E2[i] + E1[4+i]*E2[4+i];
    d0l += E0[i]*L0[i] + E0[4+i]*L1[i];
    d1v += E1[i]*V0[i] + E1[4+i]*V1[i];
    d2a += E2[i]*A0[i] + E2[4+i]*A1[i];
  }
  d01=rsum16(d01); d02=rsum16(d02); d12=rsum16(d12);
  d0l=rsum16(d0l); d1v=rsum16(d1v); d2a=rsum16(d2a);
  if (ep==0){
    float x0 = (sav+svl)*rcpf_(d02+0.5f);  // savvl
    float x1 = (sav+sal)*rcpf_(d01+0.5f);  // saavl
    float x2 = (sal+svl)*rcpf_(d12+0.5f);  // savll
    float x3 = (sav+sl )*rcpf_(d0l+0.5f);  // savl
    float x4 = (sal+sv )*rcpf_(d1v+0.5f);  // salv
    float x5 = (sa +svl)*rcpf_(d2a+0.5f);  // svla
    float mx = fmaxf(fmaxf(fmaxf(x0,x1),fmaxf(x2,x3)),fmaxf(x4,x5));
    float e0=ex2((x0-mx)*LOG2E), e1=ex2((x1-mx)*LOG2E), e2=ex2((x2-mx)*LOG2E);
    float e3=ex2((x3-mx)*LOG2E), e4=ex2((x4-mx)*LOG2E), e5=ex2((x5-mx)*LOG2E);
    float rs = rcpf_(e0+e1+e2+e3+e4+e5);
    scr[er*12+3]=e0*rs; scr[er*12+4]=e1*rs; scr[er*12+5]=e2*rs;
    scr[er*12+6]=e3*rs; scr[er*12+7]=e4*rs; scr[er*12+8]=e5*rs;
  }
  __syncthreads();   // (4) conversions + n2 ready

  // ================= P3: gf2 on 6 pairs, trimodal (single pass, round-0) =================
  const u16* h1t = wb + 24576;
  const u16* h2t = wb + 40960;
  bfrag C1[8];
  #pragma unroll
  for (int s=0;s<8;s++) C1[s] = *(const bfrag*)(h1t + (w*16+m)*256 + s*32 + q*8);
  const int S0[6] = {AV_E, AV_E, VL_E, AV_E, AL_E, VL_E};
  const int S1[6] = {VL_E, AL_E, AL_E, LS_E, VS_E, AS_E};
  facc cc1[6];
  #pragma unroll
  for (int pr=0;pr<6;pr++){ facc z = {0,0,0,0}; cc1[pr] = z; }
  #pragma unroll
  for (int s=0;s<8;s++){
    int k = s*32+q*8, ko = k&127; bool hi = (k>=128);
    #pragma unroll
    for (int pr=0;pr<6;pr++){
      const u16* sp = smu + (hi? S1[pr]:S0[pr]) + m*136 + ko;
      cc1[pr] = MFMA(*(const bfrag*)sp, C1[s], cc1[pr]);
    }
  }
  {
    float b1v = gf2_b1[w*16+m];
    #pragma unroll
    for (int pr=0;pr<6;pr++){
      #pragma unroll
      for (int r=0;r<4;r++){
        float h = cc1[pr][r]+b1v; h = fmaxf(h,0.2f*h);
        smu[HH_E + pr*1152 + (q*4+r)*72 + w*16+m] = f2b(h);  // H6
      }
    }
  }
  __syncthreads();   // (5) H6 ready; AS..VL now dead -> reusable as fusion
  facc cc2[6][2];
  #pragma unroll
  for (int pr=0;pr<6;pr++){ facc z = {0,0,0,0}; cc2[pr][0]=z; cc2[pr][1]=z; }
  #pragma unroll
  for (int s=0;s<2;s++){
    int k=s*32+q*8;
    bfrag Af[6];
    #pragma unroll
    for (int pr=0;pr<6;pr++) Af[pr] = *(const bfrag*)(smu + HH_E + pr*1152 + m*72 + k);
    #pragma unroll
    for (int t=0;t<2;t++){
      bfrag C2f = *(const bfrag*)(h2t + ((w+4*t)*16+m)*64 + s*32 + q*8);  // late load, L2-hot
      #pragma unroll
      for (int pr=0;pr<6;pr++) cc2[pr][t] = MFMA(Af[pr], C2f, cc2[pr][t]);
    }
  }
  { // trimodal -> LS_E; bim -> VS_E; uni -> AS_E   (fusion = [uni|bim|tri])
    float b2v0 = gf2_b2[w*16+m], b2v1 = gf2_b2[(w+4)*16+m];
    float tri[2][4] = {{0,0,0,0},{0,0,0,0}};
    float n2v[4][6];
    #pragma unroll
    for (int r=0;r<4;r++){
      #pragma unroll
      for (int j=0;j<6;j++) n2v[r][j] = scr[(q*4+r)*12+3+j];
    }
    #pragma unroll
    for (int pr=0;pr<6;pr++){
      #pragma unroll
      for (int t=0;t<2;t++){
        float bb = t? b2v1 : b2v0;
        #pragma unroll
        for (int r=0;r<4;r++){
          float g = ftanh(cc2[pr][t][r] + bb);
          tri[t][r] += ftanh(n2v[r][pr]*g);
        }
      }
    }
    #pragma unroll
    for (int t=0;t<2;t++){
      #pragma unroll
      for (int r=0;r<4;r++){
        smu[LS_E + (q*4+r)*136 + (w+4*t)*16+m] = f2b(tri[t][r]);
      }
    }
    u16* vp = smu + VS_E + er*136 + ep*4;
    st4b(vp,    bim8[0],bim8[1],bim8[2],bim8[3]);
    st4b(vp+64, bim8[4],bim8[5],bim8[6],bim8[7]);
    *(uint2*)(smu + AS_E + er*136 + ep*4)      = make_uint2(uni_pk[0], uni_pk[1]);
    *(uint2*)(smu + AS_E + er*136 + ep*4 + 64) = make_uint2(uni_pk[2], uni_pk[3]);
  }
  __syncthreads();   // (6) fusion complete (AS|VS|LS), H6 consumed

  // ================= P4: final head 384->64->64->128 =================
  const u16* lw1 = wb + 49152;
  const u16* lw2 = wb + 73728;
  const u16* lw3 = wb + 77824;
  {
    facc c = {0,0,0,0};
    #pragma unroll
    for (int s=0;s<12;s++){
      const int base = (s<4)? AS_E : (s<8)? VS_E : LS_E;
      bfrag Bf = *(const bfrag*)(lw1 + (w*16+m)*384 + s*32 + q*8);
      bfrag Af = *(const bfrag*)(smu + base + m*136 + (s&3)*32 + q*8);
      c = MFMA(Af, Bf, c);
    }
    float b = ll_b1[w*16+m];
    #pragma unroll
    for (int r=0;r<4;r++) smu[HH_E + (q*4+r)*72 + w*16+m] = f2b(ftanh(c[r]+b));
  }
  __syncthreads();   // (7)
  {
    facc c = {0,0,0,0};
    #pragma unroll
    for (int s=0;s<2;s++){
      bfrag Bf = *(const bfrag*)(lw2 + (w*16+m)*64 + s*32 + q*8);
      bfrag Af = *(const bfrag*)(smu + HH_E + m*72 + s*32 + q*8);
      c = MFMA(Af, Bf, c);
    }
    float b = ll_b2[w*16+m];
    #pragma unroll
    for (int r=0;r<4;r++) smu[HH_E + 1152 + (q*4+r)*72 + w*16+m] = f2b(ftanh(c[r]+b));
  }
  __syncthreads();   // (8)
  {
    facc c0={0,0,0,0}, c1={0,0,0,0};
    #pragma unroll
    for (int s=0;s<2;s++){
      bfrag Af  = *(const bfrag*)(smu + HH_E + 1152 + m*72 + s*32 + q*8);
      bfrag Bf0 = *(const bfrag*)(lw3 + (w*16+m)*64 + s*32 + q*8);
      bfrag Bf1 = *(const bfrag*)(lw3 + ((w+4)*16+m)*64 + s*32 + q*8);
      c0 = MFMA(Af, Bf0, c0);
      c1 = MFMA(Af, Bf1, c1);
    }
    float b0 = ll_b3[w*16+m], b1 = ll_b3[(w+4)*16+m];
    #pragma unroll
    for (int r=0;r<4;r++){
      out[(row0+q*4+r)*128 + w*16+m]        = ftanh(c0[r]+b0);
      out[(row0+q*4+r)*128 + (w+4)*16+m]    = ftanh(c1[r]+b1);
    }
  }
}

extern "C" void kernel_launch(void* const* d_in, const int* in_sizes, int n_in,
                              void* d_out, int out_size, void* d_ws, size_t ws_size,
                              hipStream_t stream)
{
  const float* l      = (const float*)d_in[0];
  const float* a      = (const float*)d_in[1];
  const float* v      = (const float*)d_in[2];
  const float* att_w  = (const float*)d_in[3];
  const float* att_b  = (const float*)d_in[4];
  const float* gf_w1  = (const float*)d_in[5];
  const float* gf_b1  = (const float*)d_in[6];
  const float* gf_w2  = (const float*)d_in[7];
  const float* gf_b2  = (const float*)d_in[8];
  const float* gf2_w1 = (const float*)d_in[9];
  const float* gf2_b1 = (const float*)d_in[10];
  const float* gf2_w2 = (const float*)d_in[11];
  const float* gf2_b2 = (const float*)d_in[12];
  const float* ll_w1  = (const float*)d_in[13];
  const float* ll_b1  = (const float*)d_in[14];
  const float* ll_w2  = (const float*)d_in[15];
  const float* ll_b2  = (const float*)d_in[16];
  const float* ll_w3  = (const float*)d_in[17];
  const float* ll_b3  = (const float*)d_in[18];
  u16* blob = (u16*)d_ws;

  prep_weights<<<336, 256, 0, stream>>>(gf_w1, gf_w2, gf2_w1, gf2_w2, ll_w1, ll_w2, ll_w3, blob);
  fused_graph<<<4096, 256, 0, stream>>>(l, a, v, att_w, att_b,
                                        gf_b1, gf_b2, gf2_b1, gf2_b2,
                                        ll_b1, ll_b2, ll_b3, blob, (float*)d_out);
}

// Round 7
// 245.580 us; speedup vs baseline: 1.3595x; 1.0061x over previous
//
#include <hip/hip_runtime.h>

typedef short bfrag __attribute__((ext_vector_type(8)));   // 8 x bf16 (4 VGPRs)
typedef float facc  __attribute__((ext_vector_type(4)));   // MFMA accumulator
typedef unsigned short u16;
typedef unsigned int   u32;

#define LOG2E 1.4426950408889634f
#define K2E   2.8853900817779268f   // 2*log2(e)
#define MFMA(A,B,C) __builtin_amdgcn_mfma_f32_16x16x32_bf16((A),(B),(C),0,0,0)

// ---- LDS element offsets (u16 units) — r6 map (proven 128 us) ----
#define AS_E 0
#define VS_E 2176
#define LS_E 4352
#define AV_E 6528
#define AL_E 8704
#define VL_E 10880
#define HH_E 13056
#define SCR_B 39936       // per-row scalars: [16][12] f32; [0..2]=softmax3, [4..9]=n2
#define SM_BYTES 40704

__device__ __forceinline__ float ex2(float x){ return __builtin_amdgcn_exp2f(x); }
__device__ __forceinline__ float rcpf_(float x){ return __builtin_amdgcn_rcpf(x); }
// tanh from PRE-SCALED arg y = x*2log2e (bias folded by caller via fma)
__device__ __forceinline__ float ftanh_s(float y){ return 1.0f - 2.0f*rcpf_(ex2(y) + 1.0f); }
// tanh for |y| <= 1 (softmax-weight * tanh product): Pade(5,4), max err ~1e-6, 1 trans
__device__ __forceinline__ float ftanhb(float y){
  float y2 = y*y, y4 = y2*y2;
  float n = (y2*105.f + 945.f) + y4;
  float d = (y2*420.f + 945.f) + y4*15.f;
  return y*n*rcpf_(d);
}
__device__ __forceinline__ u16 f2b(float x){ return (u16)((__float_as_uint(x) + 0x8000u)>>16); }
__device__ __forceinline__ float b2f(u16 b){ return __uint_as_float(((u32)b)<<16); }
__device__ __forceinline__ u32 pk2(float x0, float x1){
  return __builtin_amdgcn_perm(__float_as_uint(x1)+0x8000u, __float_as_uint(x0)+0x8000u, 0x07060302u);
}
// 16-lane reductions via DPP row_ror (VALU pipe, not LDS)
template<int N>
__device__ __forceinline__ float ror16f(float v){
  return __int_as_float(__builtin_amdgcn_update_dpp(0, __float_as_int(v), 0x120|N, 0xF, 0xF, false));
}
__device__ __forceinline__ float rsum16(float v){
  v += ror16f<8>(v); v += ror16f<4>(v); v += ror16f<2>(v); v += ror16f<1>(v); return v;
}
__device__ __forceinline__ void st4b(u16* p, float x0,float x1,float x2,float x3){
  *(uint2*)p = make_uint2(pk2(x0,x1), pk2(x2,x3));
}

// ---- prep: transpose weights to bf16 [n][k] blobs; coalesced reads ----
__global__ void prep_weights(const float* __restrict__ gf_w1, const float* __restrict__ gf_w2,
                             const float* __restrict__ gf2_w1, const float* __restrict__ gf2_w2,
                             const float* __restrict__ ll_w1, const float* __restrict__ ll_w2,
                             const float* __restrict__ ll_w3, u16* __restrict__ blob)
{
  u32 i = blockIdx.x*256u + threadIdx.x;
  if (i >= 86016u) return;
  u32 off, K, ln; const float* src;   // ln = log2(N)
  if      (i < 16384u){ off=0u;     K=256u; ln=6u; src=gf_w1; }
  else if (i < 24576u){ off=16384u; K=64u;  ln=7u; src=gf_w2; }
  else if (i < 40960u){ off=24576u; K=256u; ln=6u; src=gf2_w1; }
  else if (i < 49152u){ off=40960u; K=64u;  ln=7u; src=gf2_w2; }
  else if (i < 73728u){ off=49152u; K=384u; ln=6u; src=ll_w1; }
  else if (i < 77824u){ off=73728u; K=64u;  ln=6u; src=ll_w2; }
  else               { off=77824u; K=64u;  ln=7u; src=ll_w3; }
  u32 li = i - off;
  u32 k = li >> ln, n = li & ((1u<<ln)-1u);
  blob[off + n*K + k] = f2b(src[li]);
}

__global__ __launch_bounds__(256,4) void fused_graph(
    const float* __restrict__ Lg, const float* __restrict__ Ag, const float* __restrict__ Vg,
    const float* __restrict__ att_w, const float* __restrict__ att_b,
    const float* __restrict__ gf_b1, const float* __restrict__ gf_b2,
    const float* __restrict__ gf2_b1, const float* __restrict__ gf2_b2,
    const float* __restrict__ ll_b1, const float* __restrict__ ll_b2, const float* __restrict__ ll_b3,
    const u16* __restrict__ wb, float* __restrict__ out)
{
  __shared__ alignas(16) char sm[SM_BYTES];
  u16* smu = (u16*)sm;
  float* scr = (float*)(sm + SCR_B);

  const int tid = threadIdx.x;
  const int lane = tid & 63;
  const int w = tid >> 6;        // wave 0..3
  const int m = lane & 15;       // MFMA row(A)/col(B)/col(C)
  const int q = lane >> 4;       // quad
  const int er = tid >> 4;       // elementwise row 0..15
  const int ep = tid & 15;       // elementwise lane-in-row
  const int row0 = blockIdx.x << 4;

  // ================= P0: attention scalars, unimodal(->regs), softmaxes, dots =================
  const int gb = (row0 + er)*128 + ep*4;
  facc A0 = *(const facc*)(Ag+gb), A1 = *(const facc*)(Ag+gb+64);
  facc V0 = *(const facc*)(Vg+gb), V1 = *(const facc*)(Vg+gb+64);
  facc L0 = *(const facc*)(Lg+gb), L1 = *(const facc*)(Lg+gb+64);
  facc W0 = *(const facc*)(att_w+ep*4), W1 = *(const facc*)(att_w+ep*4+64);
  float abK = att_b[0]*K2E;
  float pa=0.f,pv=0.f,pl=0.f;
  #pragma unroll
  for (int i=0;i<4;i++){ pa += A0[i]*W0[i]+A1[i]*W1[i]; pv += V0[i]*W0[i]+V1[i]*W1[i]; pl += L0[i]*W0[i]+L1[i]*W1[i]; }
  float sa = ftanh_s(rsum16(pa)*K2E + abK);
  float sv = ftanh_s(rsum16(pv)*K2E + abK);
  float sl = ftanh_s(rsum16(pl)*K2E + abK);
  u32 uni_pk[4];
  {
    const float th = 1.0f/3.0f;
    uni_pk[0] = pk2((sa*A0[0]+sv*V0[0]+sl*L0[0])*th, (sa*A0[1]+sv*V0[1]+sl*L0[1])*th);
    uni_pk[1] = pk2((sa*A0[2]+sv*V0[2]+sl*L0[2])*th, (sa*A0[3]+sv*V0[3]+sl*L0[3])*th);
    uni_pk[2] = pk2((sa*A1[0]+sv*V1[0]+sl*L1[0])*th, (sa*A1[1]+sv*V1[1]+sl*L1[1])*th);
    uni_pk[3] = pk2((sa*A1[2]+sv*V1[2]+sl*L1[2])*th, (sa*A1[3]+sv*V1[3]+sl*L1[3])*th);
  }
  // max-free softmax: inputs ~N(0,1), |x|<~6 -> e^x fine in f32 (no overflow risk)
  #define SMAX(X0,X1,OFFE) { \
    float s_=0.f; \
    _Pragma("unroll") for (int i=0;i<4;i++){ X0[i]=ex2(X0[i]*LOG2E); X1[i]=ex2(X1[i]*LOG2E); s_+=X0[i]+X1[i]; } \
    s_ = rsum16(s_); float rs_ = rcpf_(s_); \
    _Pragma("unroll") for (int i=0;i<4;i++){ X0[i]*=rs_; X1[i]*=rs_; } \
    u16* dp_ = smu + (OFFE) + er*136 + ep*4; \
    st4b(dp_, X0[0],X0[1],X0[2],X0[3]); st4b(dp_+64, X1[0],X1[1],X1[2],X1[3]); }
  SMAX(A0,A1,AS_E)
  SMAX(V0,V1,VS_E)
  SMAX(L0,L1,LS_E)
  float dav=0.f,dal=0.f,dvl=0.f;
  #pragma unroll
  for (int i=0;i<4;i++){ dav += A0[i]*V0[i]+A1[i]*V1[i]; dal += A0[i]*L0[i]+A1[i]*L1[i]; dvl += V0[i]*L0[i]+V1[i]*L1[i]; }
  dav = rsum16(dav); dal = rsum16(dal); dvl = rsum16(dvl);
  float sav = (sa+sv)*rcpf_(dav+0.5f);
  float sal = (sa+sl)*rcpf_(dal+0.5f);
  float svl = (sl+sv)*rcpf_(dvl+0.5f);
  if (ep==0){
    // |sav..svl| <= 4 -> max-free softmax3
    float e0 = ex2(sav*LOG2E), e1 = ex2(sal*LOG2E), e2 = ex2(svl*LOG2E);
    float rs = rcpf_(e0+e1+e2);
    scr[er*12+0]=e0*rs; scr[er*12+1]=e1*rs; scr[er*12+2]=e2*rs;
  }
  __syncthreads();   // (1) softmaxes+scr ready

  // ================= P1: gf on 3 pairs =================
  const u16* g1t = wb;            // [64][256]
  const u16* g2t = wb + 16384;    // [128][64]
  bfrag B1[8];
  #pragma unroll
  for (int s=0;s<8;s++) B1[s] = *(const bfrag*)(g1t + (w*16+m)*256 + s*32 + q*8);
  facc acc0={0,0,0,0}, acc1={0,0,0,0}, acc2={0,0,0,0};
  #pragma unroll
  for (int s=0;s<8;s++){
    int k = s*32 + q*8, ko = k & 127; bool hi = (k >= 128);
    const u16* p0 = smu + (hi? VS_E:AS_E) + m*136 + ko;  // (a',v')
    const u16* p1 = smu + (hi? LS_E:AS_E) + m*136 + ko;  // (a',l')
    const u16* p2 = smu + (hi? LS_E:VS_E) + m*136 + ko;  // (v',l')
    acc0 = MFMA(*(const bfrag*)p0, B1[s], acc0);
    acc1 = MFMA(*(const bfrag*)p1, B1[s], acc1);
    acc2 = MFMA(*(const bfrag*)p2, B1[s], acc2);
  }
  { // leaky_relu -> H3 @ HH_E (stride 72)
    float b1v = gf_b1[w*16+m];
    #pragma unroll
    for (int r=0;r<4;r++){
      int rr = q*4+r;
      float h0 = acc0[r]+b1v; h0 = fmaxf(h0, 0.2f*h0);
      float h1 = acc1[r]+b1v; h1 = fmaxf(h1, 0.2f*h1);
      float h2 = acc2[r]+b1v; h2 = fmaxf(h2, 0.2f*h2);
      smu[HH_E + 0*1152 + rr*72 + w*16+m] = f2b(h0);
      smu[HH_E + 1*1152 + rr*72 + w*16+m] = f2b(h1);
      smu[HH_E + 2*1152 + rr*72 + w*16+m] = f2b(h2);
    }
  }
  __syncthreads();   // (2) H3 ready
  facc c2[3][2] = {{{0,0,0,0},{0,0,0,0}},{{0,0,0,0},{0,0,0,0}},{{0,0,0,0},{0,0,0,0}}};
  #pragma unroll
  for (int s=0;s<2;s++){
    int k = s*32 + q*8;
    bfrag Af0 = *(const bfrag*)(smu + HH_E + 0*1152 + m*72 + k);
    bfrag Af1 = *(const bfrag*)(smu + HH_E + 1*1152 + m*72 + k);
    bfrag Af2 = *(const bfrag*)(smu + HH_E + 2*1152 + m*72 + k);
    #pragma unroll
    for (int t=0;t<2;t++){
      bfrag B2f = *(const bfrag*)(g2t + ((w+4*t)*16+m)*64 + s*32 + q*8);  // late load, L2-hot
      c2[0][t] = MFMA(Af0, B2f, c2[0][t]);
      c2[1][t] = MFMA(Af1, B2f, c2[1][t]);
      c2[2][t] = MFMA(Af2, B2f, c2[2][t]);
    }
  }
  // NO barrier: raw G goes to AV/AL/VL (first write to that region); H3 reads were in-wave.
  {
    float b2v0s = gf_b2[w*16+m]*K2E, b2v1s = gf_b2[(w+4)*16+m]*K2E;
    #pragma unroll
    for (int p3=0;p3<3;p3++){
      #pragma unroll
      for (int t=0;t<2;t++){
        float bbs = t? b2v1s : b2v0s;
        int cc = (w+4*t)*16+m;
        #pragma unroll
        for (int r=0;r<4;r++){
          smu[AV_E + p3*2176 + (q*4+r)*136 + cc] = f2b(ftanh_s(c2[p3][t][r]*K2E + bbs));
        }
      }
    }
  }
  __syncthreads();   // (3) raw G ready

  // ======== P2: max-free softmax stats of G + IN-PLACE conversion + dots + n2 ========
  // g in (-1,1): e = exp2(g*log2e), no max. E kept UNNORMALIZED; 1/S folded into dots.
  float E0[8], E1[8], E2[8], bim8[8];
  float RS0, RS1, RS2;
  #pragma unroll
  for (int j=0;j<8;j++) bim8[j]=0.f;
  #define GSTATC(EA, G3, RS) { \
    u16* gpa_ = smu + AV_E + (G3)*2176 + er*136 + ep*4; \
    u16* gpb_ = gpa_ + 64; \
    ushort4 ga_ = *(const ushort4*)gpa_; ushort4 gb_ = *(const ushort4*)gpb_; \
    float x_[8]; \
    x_[0]=b2f(ga_.x); x_[1]=b2f(ga_.y); x_[2]=b2f(ga_.z); x_[3]=b2f(ga_.w); \
    x_[4]=b2f(gb_.x); x_[5]=b2f(gb_.y); x_[6]=b2f(gb_.z); x_[7]=b2f(gb_.w); \
    float nn_ = scr[er*12+(G3)]; \
    float t_[8]; \
    _Pragma("unroll") for (int j=0;j<8;j++){ t_[j]=ftanhb(nn_*x_[j]); bim8[j]+=t_[j]; } \
    st4b(gpa_, t_[0],t_[1],t_[2],t_[3]); \
    st4b(gpb_, t_[4],t_[5],t_[6],t_[7]); \
    float s_=0.f; \
    _Pragma("unroll") for (int j=0;j<8;j++){ x_[j]=ex2(x_[j]*LOG2E); s_+=x_[j]; } \
    s_ = rsum16(s_); RS = rcpf_(s_); \
    _Pragma("unroll") for (int j=0;j<8;j++) EA[j]=x_[j]; }
  GSTATC(E0,0,RS0)
  GSTATC(E1,1,RS1)
  GSTATC(E2,2,RS2)
  float d01=0.f,d02=0.f,d12=0.f,d0l=0.f,d1v=0.f,d2a=0.f;
  #pragma unroll
  for (int i=0;i<4;i++){
    d01 += E0[i]*E1[i] + E0[4+i]*E1[4+i];
    d02 += E0[i]*E2[i] + E0[4+i]*E2[4+i];
    d12 += E1[i]*E2[i] + E1[4+i]*E2[4+i];
    d0l += E0[i]*L0[i] + E0[4+i]*L1[i];
    d1v += E1[i]*V0[i] + E1[4+i]*V1[i];
    d2a += E2[i]*A0[i] + E2[4+i]*A1[i];
  }
  d01=rsum16(d01)*(RS0*RS1); d02=rsum16(d02)*(RS0*RS2); d12=rsum16(d12)*(RS1*RS2);
  d0l=rsum16(d0l)*RS0;       d1v=rsum16(d1v)*RS1;       d2a=rsum16(d2a)*RS2;
  if (ep==0){
    float x0 = (sav+svl)*rcpf_(d02+0.5f);  // savvl
    float x1 = (sav+sal)*rcpf_(d01+0.5f);  // saavl
    float x2 = (sal+svl)*rcpf_(d12+0.5f);  // savll
    float x3 = (sav+sl )*rcpf_(d0l+0.5f);  // savl
    float x4 = (sal+sv )*rcpf_(d1v+0.5f);  // salv
    float x5 = (sa +svl)*rcpf_(d2a+0.5f);  // svla
    // |x_j| <= 16 -> max-free softmax6 (e^16 ~ 9e6, safe in f32)
    float e0=ex2(x0*LOG2E), e1=ex2(x1*LOG2E), e2=ex2(x2*LOG2E);
    float e3=ex2(x3*LOG2E), e4=ex2(x4*LOG2E), e5=ex2(x5*LOG2E);
    float rs = rcpf_(e0+e1+e2+e3+e4+e5);
    scr[er*12+4]=e0*rs; scr[er*12+5]=e1*rs; scr[er*12+6]=e2*rs;
    scr[er*12+7]=e3*rs; scr[er*12+8]=e4*rs; scr[er*12+9]=e5*rs;
  }
  __syncthreads();   // (4) conversions + n2 (scr[4..9]) ready

  // ================= P3: gf2 on 6 pairs, trimodal =================
  const u16* h1t = wb + 24576;
  const u16* h2t = wb + 40960;
  bfrag C1[8];
  #pragma unroll
  for (int s=0;s<8;s++) C1[s] = *(const bfrag*)(h1t + (w*16+m)*256 + s*32 + q*8);
  const int S0[6] = {AV_E, AV_E, VL_E, AV_E, AL_E, VL_E};
  const int S1[6] = {VL_E, AL_E, AL_E, LS_E, VS_E, AS_E};
  facc cc1[6];
  #pragma unroll
  for (int pr=0;pr<6;pr++){ facc z = {0,0,0,0}; cc1[pr] = z; }
  #pragma unroll
  for (int s=0;s<8;s++){
    int k = s*32+q*8, ko = k&127; bool hi = (k>=128);
    #pragma unroll
    for (int pr=0;pr<6;pr++){
      const u16* sp = smu + (hi? S1[pr]:S0[pr]) + m*136 + ko;
      cc1[pr] = MFMA(*(const bfrag*)sp, C1[s], cc1[pr]);
    }
  }
  {
    float b1v = gf2_b1[w*16+m];
    #pragma unroll
    for (int pr=0;pr<6;pr++){
      #pragma unroll
      for (int r=0;r<4;r++){
        float h = cc1[pr][r]+b1v; h = fmaxf(h,0.2f*h);
        smu[HH_E + pr*1152 + (q*4+r)*72 + w*16+m] = f2b(h);  // H6
      }
    }
  }
  __syncthreads();   // (5) H6 ready; AS..VL now dead -> reusable as fusion
  facc cc2[6][2];
  #pragma unroll
  for (int pr=0;pr<6;pr++){ facc z = {0,0,0,0}; cc2[pr][0]=z; cc2[pr][1]=z; }
  #pragma unroll
  for (int s=0;s<2;s++){
    int k=s*32+q*8;
    bfrag Af[6];
    #pragma unroll
    for (int pr=0;pr<6;pr++) Af[pr] = *(const bfrag*)(smu + HH_E + pr*1152 + m*72 + k);
    #pragma unroll
    for (int t=0;t<2;t++){
      bfrag C2f = *(const bfrag*)(h2t + ((w+4*t)*16+m)*64 + s*32 + q*8);  // late load, L2-hot
      #pragma unroll
      for (int pr=0;pr<6;pr++) cc2[pr][t] = MFMA(Af[pr], C2f, cc2[pr][t]);
    }
  }
  { // trimodal -> LS_E; bim -> VS_E; uni -> AS_E   (fusion = [uni|bim|tri])
    float b2v0s = gf2_b2[w*16+m]*K2E, b2v1s = gf2_b2[(w+4)*16+m]*K2E;
    float tri[2][4] = {{0,0,0,0},{0,0,0,0}};
    float n2v[4][6];
    #pragma unroll
    for (int r=0;r<4;r++){
      const float4 v4 = *(const float4*)(scr + (q*4+r)*12 + 4);
      const float2 v2 = *(const float2*)(scr + (q*4+r)*12 + 8);
      n2v[r][0]=v4.x; n2v[r][1]=v4.y; n2v[r][2]=v4.z; n2v[r][3]=v4.w;
      n2v[r][4]=v2.x; n2v[r][5]=v2.y;
    }
    #pragma unroll
    for (int pr=0;pr<6;pr++){
      #pragma unroll
      for (int t=0;t<2;t++){
        float bbs = t? b2v1s : b2v0s;
        #pragma unroll
        for (int r=0;r<4;r++){
          float g = ftanh_s(cc2[pr][t][r]*K2E + bbs);
          tri[t][r] += ftanhb(n2v[r][pr]*g);
        }
      }
    }
    #pragma unroll
    for (int t=0;t<2;t++){
      #pragma unroll
      for (int r=0;r<4;r++){
        smu[LS_E + (q*4+r)*136 + (w+4*t)*16+m] = f2b(tri[t][r]);
      }
    }
    u16* vp = smu + VS_E + er*136 + ep*4;
    st4b(vp,    bim8[0],bim8[1],bim8[2],bim8[3]);
    st4b(vp+64, bim8[4],bim8[5],bim8[6],bim8[7]);
    *(uint2*)(smu + AS_E + er*136 + ep*4)      = make_uint2(uni_pk[0], uni_pk[1]);
    *(uint2*)(smu + AS_E + er*136 + ep*4 + 64) = make_uint2(uni_pk[2], uni_pk[3]);
  }
  __syncthreads();   // (6) fusion complete (AS|VS|LS), H6 consumed

  // ================= P4: final head 384->64->64->128 =================
  const u16* lw1 = wb + 49152;
  const u16* lw2 = wb + 73728;
  const u16* lw3 = wb + 77824;
  {
    facc c = {0,0,0,0};
    #pragma unroll
    for (int s=0;s<12;s++){
      const int base = (s<4)? AS_E : (s<8)? VS_E : LS_E;
      bfrag Bf = *(const bfrag*)(lw1 + (w*16+m)*384 + s*32 + q*8);
      bfrag Af = *(const bfrag*)(smu + base + m*136 + (s&3)*32 + q*8);
      c = MFMA(Af, Bf, c);
    }
    float bs = ll_b1[w*16+m]*K2E;
    #pragma unroll
    for (int r=0;r<4;r++) smu[HH_E + (q*4+r)*72 + w*16+m] = f2b(ftanh_s(c[r]*K2E + bs));
  }
  __syncthreads();   // (7)
  {
    facc c = {0,0,0,0};
    #pragma unroll
    for (int s=0;s<2;s++){
      bfrag Bf = *(const bfrag*)(lw2 + (w*16+m)*64 + s*32 + q*8);
      bfrag Af = *(const bfrag*)(smu + HH_E + m*72 + s*32 + q*8);
      c = MFMA(Af, Bf, c);
    }
    float bs = ll_b2[w*16+m]*K2E;
    #pragma unroll
    for (int r=0;r<4;r++) smu[HH_E + 1152 + (q*4+r)*72 + w*16+m] = f2b(ftanh_s(c[r]*K2E + bs));
  }
  __syncthreads();   // (8)
  {
    facc c0={0,0,0,0}, c1={0,0,0,0};
    #pragma unroll
    for (int s=0;s<2;s++){
      bfrag Af  = *(const bfrag*)(smu + HH_E + 1152 + m*72 + s*32 + q*8);
      bfrag Bf0 = *(const bfrag*)(lw3 + (w*16+m)*64 + s*32 + q*8);
      bfrag Bf1 = *(const bfrag*)(lw3 + ((w+4)*16+m)*64 + s*32 + q*8);
      c0 = MFMA(Af, Bf0, c0);
      c1 = MFMA(Af, Bf1, c1);
    }
    float b0s = ll_b3[w*16+m]*K2E, b1s = ll_b3[(w+4)*16+m]*K2E;
    #pragma unroll
    for (int r=0;r<4;r++){
      out[(row0+q*4+r)*128 + w*16+m]        = ftanh_s(c0[r]*K2E + b0s);
      out[(row0+q*4+r)*128 + (w+4)*16+m]    = ftanh_s(c1[r]*K2E + b1s);
    }
  }
}

extern "C" void kernel_launch(void* const* d_in, const int* in_sizes, int n_in,
                              void* d_out, int out_size, void* d_ws, size_t ws_size,
                              hipStream_t stream)
{
  const float* l      = (const float*)d_in[0];
  const float* a      = (const float*)d_in[1];
  const float* v      = (const float*)d_in[2];
  const float* att_w  = (const float*)d_in[3];
  const float* att_b  = (const float*)d_in[4];
  const float* gf_w1  = (const float*)d_in[5];
  const float* gf_b1  = (const float*)d_in[6];
  const float* gf_w2  = (const float*)d_in[7];
  const float* gf_b2  = (const float*)d_in[8];
  const float* gf2_w1 = (const float*)d_in[9];
  const float* gf2_b1 = (const float*)d_in[10];
  const float* gf2_w2 = (const float*)d_in[11];
  const float* gf2_b2 = (const float*)d_in[12];
  const float* ll_w1  = (const float*)d_in[13];
  const float* ll_b1  = (const float*)d_in[14];
  const float* ll_w2  = (const float*)d_in[15];
  const float* ll_b2  = (const float*)d_in[16];
  const float* ll_w3  = (const float*)d_in[17];
  const float* ll_b3  = (const float*)d_in[18];
  u16* blob = (u16*)d_ws;

  prep_weights<<<336, 256, 0, stream>>>(gf_w1, gf_w2, gf2_w1, gf2_w2, ll_w1, ll_w2, ll_w3, blob);
  fused_graph<<<4096, 256, 0, stream>>>(l, a, v, att_w, att_b,
                                        gf_b1, gf_b2, gf2_b1, gf2_b2,
                                        ll_b1, ll_b2, ll_b3, blob, (float*)d_out);
}